// Round 2
// baseline (93.138 us; speedup 1.0000x reference)
//
#include <hip/hip_runtime.h>
#include <stdint.h>

constexpr int K      = 49;          // 7x7 kernel flattened
constexpr int C      = 32;          // out channels
constexpr int WPT    = 64;          // windows per tile = lanes per wave
constexpr int TILE_F = WPT * K;     // 3136 floats = 12544 B per tile
constexpr int GRID   = 1536;        // 6 blocks/CU * 256 CUs -> all co-resident

#define GPTR(p) ((const __attribute__((address_space(1))) uint32_t*)(p))
#define LPTR(p) ((__attribute__((address_space(3))) uint32_t*)(p))

// Stage one 12544 B tile global->LDS asynchronously: 12 x 16B + 1 x 4B = 13 VMEM ops.
// Per-lane LDS dest is linear (base + lane*size) as global_load_lds requires.
__device__ __forceinline__ void prefetch_tile(const float* __restrict__ g,
                                              float* lds, int lane) {
#pragma unroll
    for (int r = 0; r < 12; ++r) {
        __builtin_amdgcn_global_load_lds(GPTR(g + r * 256 + lane * 4),
                                         LPTR(lds + r * 256 + lane * 4),
                                         16, 0, 0);
    }
    __builtin_amdgcn_global_load_lds(GPTR(g + 12 * 256 + lane),
                                     LPTR(lds + 12 * 256 + lane),
                                     4, 0, 0);
}

__global__ __launch_bounds__(WPT) void conv2d_im2col_pers(
    const float* __restrict__ enc_x,
    const float* __restrict__ weight,   // [C*K] wave-uniform -> s_load
    const float* __restrict__ bias,     // [C]
    float* __restrict__ out,            // [C * windows_nb]
    int windows_nb)
{
    __shared__ __align__(16) float xsA[TILE_F];   // double buffer: 2 x 12544 B
    __shared__ __align__(16) float xsB[TILE_F];   // -> 25088 B/block, 6 blocks/CU

    const int lane   = threadIdx.x;
    const int wid    = blockIdx.x;                 // one wave per block
    const int ntiles = windows_nb / WPT;           // 16384
    const int nt     = (ntiles - wid + GRID - 1) / GRID;   // 10 or 11 tiles/wave

    // Prologue: fill both buffers (tiles j=0 and j=1).
    prefetch_tile(enc_x + (size_t)wid * TILE_F, xsA, lane);
    if (nt > 1)
        prefetch_tile(enc_x + (size_t)(wid + GRID) * TILE_F, xsB, lane);

    // One pipeline stage. vmcnt accounting (FIFO, per wave):
    //   j==0     : outstanding after loads_0 = loads_1 (13)            -> vmcnt(13)
    //   steady   : after loads_j = stores_{j-1}(32) + loads_{j+1}(13)  -> vmcnt(45)
    //   j==nt-1  : after loads_last = stores_{nt-2}(32)                -> vmcnt(32)
    auto body = [&](float* buf, int j) {
        const long tile = wid + (long)j * GRID;

        if (j == 0)            asm volatile("s_waitcnt vmcnt(13)" ::: "memory");
        else if (j == nt - 1)  asm volatile("s_waitcnt vmcnt(32)" ::: "memory");
        else                   asm volatile("s_waitcnt vmcnt(45)" ::: "memory");

        // Pull this thread's window row into registers.
        // LDS bank pattern (lane*49+k)%32: gcd(49,32)=1 -> 2 lanes/bank (free).
        float x[K];
#pragma unroll
        for (int k = 0; k < K; ++k) x[k] = buf[lane * K + k];

        const size_t w = (size_t)tile * WPT + lane;

        for (int c = 0; c < C; ++c) {
            const float* wc = weight + c * K;
            float a0 = 0.f, a1 = 0.f, a2 = 0.f, a3 = 0.f;
#pragma unroll
            for (int k = 0; k < K; k += 4) {
                a0 = fmaf(x[k], wc[k], a0);
                if (k + 1 < K) a1 = fmaf(x[k + 1], wc[k + 1], a1);
                if (k + 2 < K) a2 = fmaf(x[k + 2], wc[k + 2], a2);
                if (k + 3 < K) a3 = fmaf(x[k + 3], wc[k + 3], a3);
            }
            out[(size_t)c * windows_nb + w] = (a0 + a1) + (a2 + a3) + bias[c];
        }

        // Keep stores (32 VMEM) ordered BEFORE the next prefetch so the
        // vmcnt counts above stay exact.
        asm volatile("" ::: "memory");

        if (j + 2 < nt)
            prefetch_tile(enc_x + (size_t)(tile + 2 * GRID) * TILE_F, buf, lane);
    };

    // 2x unrolled so buffer pointers are compile-time (no runtime LDS select).
    int j = 0;
    for (; j + 1 < nt; j += 2) {
        body(xsA, j);
        body(xsB, j + 1);
    }
    if (j < nt) body(xsA, j);   // odd nt tail (j even -> xsA, parity correct)
}

extern "C" void kernel_launch(void* const* d_in, const int* in_sizes, int n_in,
                              void* d_out, int out_size, void* d_ws, size_t ws_size,
                              hipStream_t stream) {
    const float* enc_x  = (const float*)d_in[0];
    const float* weight = (const float*)d_in[1];   // [C,7,7] flat
    const float* bias   = (const float*)d_in[2];   // [C]
    float* out = (float*)d_out;

    const int windows_nb = in_sizes[0] / K;        // 1048576

    conv2d_im2col_pers<<<GRID, WPT, 0, stream>>>(enc_x, weight, bias, out, windows_nb);
}